// Round 2
// baseline (2825.700 us; speedup 1.0000x reference)
//
#include <hip/hip_runtime.h>
#include <hip/hip_bf16.h>

#define D_IN 256
#define D_OUT 128
#define LN_EPS 1e-5f

typedef short bf16x8 __attribute__((ext_vector_type(8)));
typedef float f32x4 __attribute__((ext_vector_type(4)));
typedef unsigned short ushort_t;

__device__ __forceinline__ float b2f(ushort_t u) {
    union { unsigned int i; float f; } v; v.i = (unsigned int)u << 16; return v.f;
}
__device__ __forceinline__ ushort_t f2b(float f) {
    __hip_bfloat16 h = __float2bfloat16(f);
    return *reinterpret_cast<ushort_t*>(&h);
}

// ---------------- Kernel 0: pack+transpose f32 weights into bf16 Wt[n][k], n = [W | res_w] cols
__global__ void k_transpose(const float* __restrict__ w, const float* __restrict__ rw,
                            ushort_t* __restrict__ wt) {
    int idx = blockIdx.x * 256 + threadIdx.x;   // 65536 total
    int n = idx >> 8, k = idx & 255;
    float v = (n < 128) ? w[k * 128 + n] : rw[k * 128 + (n - 128)];
    wt[idx] = f2b(v);
}

// ---------------- Kernel 1: dual GEMM (bf16 MFMA internally, f32 in/out)
// support(bf16) = x@W ; out(f32) = bias + relu(x@res_w + res_b)
__launch_bounds__(256)
__global__ void k_gemm(const float* __restrict__ x, const ushort_t* __restrict__ wt,
                       const float* __restrict__ bias, const float* __restrict__ res_b,
                       ushort_t* __restrict__ support, float* __restrict__ out, int n_nodes) {
    __shared__ ushort_t As[64 * 40];    // 64 rows x 32 k bf16, stride 40 (2-way bank alias only)
    __shared__ ushort_t Bs[256 * 40];   // 256 n  x 32 k bf16, stride 40

    const int tid = threadIdx.x;
    const int m0 = blockIdx.x * 64;
    const int wv = tid >> 6, lane = tid & 63;
    const int lm = lane & 15, quad = lane >> 4;
    const int mh = wv >> 1;   // m-half: rows mh*32 .. +32
    const int nh = wv & 1;    // n-half: cols nh*128 .. +128

    f32x4 acc[2][8];
#pragma unroll
    for (int i = 0; i < 2; i++)
#pragma unroll
        for (int j = 0; j < 8; j++) acc[i][j] = 0.0f;

    const int arow = tid >> 2, aseg = tid & 3;
    const bool arow_ok = (m0 + arow) < n_nodes;
    const float* xrow = x + (long)(m0 + arow) * D_IN + aseg * 8;

    for (int kc = 0; kc < 8; kc++) {
        __syncthreads();
        // stage A: 64x32, f32 -> bf16
        {
            bf16x8 av = {0, 0, 0, 0, 0, 0, 0, 0};
            if (arow_ok) {
                f32x4 p0 = *(const f32x4*)(xrow + kc * 32);
                f32x4 p1 = *(const f32x4*)(xrow + kc * 32 + 4);
#pragma unroll
                for (int j = 0; j < 4; j++) { av[j] = (short)f2b(p0[j]); av[4 + j] = (short)f2b(p1[j]); }
            }
            *(bf16x8*)(&As[arow * 40 + aseg * 8]) = av;
        }
        // stage B: 256x32 bf16 from Wt[n][k]
#pragma unroll
        for (int i = 0; i < 4; i++) {
            int n = (tid >> 2) + i * 64;
            bf16x8 v = *(const bf16x8*)(wt + n * 256 + kc * 32 + aseg * 8);
            *(bf16x8*)(&Bs[n * 40 + aseg * 8]) = v;
        }
        __syncthreads();

        bf16x8 afr0 = *(const bf16x8*)(&As[(mh * 32 + lm) * 40 + quad * 8]);
        bf16x8 afr1 = *(const bf16x8*)(&As[(mh * 32 + 16 + lm) * 40 + quad * 8]);
#pragma unroll
        for (int nt = 0; nt < 8; nt++) {
            bf16x8 bfr = *(const bf16x8*)(&Bs[(nh * 128 + nt * 16 + lm) * 40 + quad * 8]);
            acc[0][nt] = __builtin_amdgcn_mfma_f32_16x16x32_bf16(afr0, bfr, acc[0][nt], 0, 0, 0);
            acc[1][nt] = __builtin_amdgcn_mfma_f32_16x16x32_bf16(afr1, bfr, acc[1][nt], 0, 0, 0);
        }
    }

    // epilogue: C/D layout col=lane&15, row=quad*4+reg  [m89/m91-verified]
#pragma unroll
    for (int i = 0; i < 2; i++) {
#pragma unroll
        for (int nt = 0; nt < 8; nt++) {
            int col = nh * 128 + nt * 16 + lm;
#pragma unroll
            for (int r = 0; r < 4; r++) {
                int node = m0 + mh * 32 + i * 16 + quad * 4 + r;
                if (node >= n_nodes) continue;
                float v = acc[i][nt][r];
                if (col < 128) {
                    support[(long)node * 128 + col] = f2b(v);
                } else {
                    int c2 = col - 128;
                    float t = v + res_b[c2];
                    t = t > 0.0f ? t : 0.0f;
                    out[(long)node * 128 + c2] = t + bias[c2];
                }
            }
        }
    }
}

// ---------------- Kernel 2: scatter-add  out[dst] += w_e * support[src]   (wave per edge)
__launch_bounds__(256)
__global__ void k_scatter(const ushort_t* __restrict__ support, const float* __restrict__ ew,
                          const int* __restrict__ ei, float* __restrict__ out, int E) {
    int gw = (int)((blockIdx.x * blockDim.x + threadIdx.x) >> 6);
    int lane = threadIdx.x & 63;
    int nw = (int)((gridDim.x * blockDim.x) >> 6);
    for (int e = gw; e < E; e += nw) {
        int src = ei[e];
        int dst = ei[E + e];
        float w = ew[e];
        unsigned int v = *(const unsigned int*)(support + (long)src * 128 + lane * 2);
        float lo = b2f((ushort_t)(v & 0xffffu));
        float hi = b2f((ushort_t)(v >> 16));
        float* p = out + (long)dst * 128 + lane * 2;
        unsafeAtomicAdd(p, w * lo);
        unsafeAtomicAdd(p + 1, w * hi);
    }
}

// ---------------- Kernel 3: LayerNorm over 128 feats, wave per node, in-place f32
__launch_bounds__(256)
__global__ void k_ln(float* __restrict__ out, const float* __restrict__ gamma,
                     const float* __restrict__ beta, int n_nodes) {
    int gw = (int)((blockIdx.x * blockDim.x + threadIdx.x) >> 6);
    int lane = threadIdx.x & 63;
    int nw = (int)((gridDim.x * blockDim.x) >> 6);
    float g0 = gamma[lane * 2], g1 = gamma[lane * 2 + 1];
    float b0 = beta[lane * 2], b1 = beta[lane * 2 + 1];
    for (int node = gw; node < n_nodes; node += nw) {
        float2 v = *(const float2*)(out + (long)node * 128 + lane * 2);
        float s = v.x + v.y;
        float ss = v.x * v.x + v.y * v.y;
#pragma unroll
        for (int off = 1; off < 64; off <<= 1) {
            s += __shfl_xor(s, off, 64);
            ss += __shfl_xor(ss, off, 64);
        }
        float mean = s * (1.0f / 128.0f);
        float var = ss * (1.0f / 128.0f) - mean * mean;
        float rstd = rsqrtf(var + LN_EPS);
        float2 o;
        o.x = (v.x - mean) * rstd * g0 + b0;
        o.y = (v.y - mean) * rstd * g1 + b1;
        *(float2*)(out + (long)node * 128 + lane * 2) = o;
    }
}

extern "C" void kernel_launch(void* const* d_in, const int* in_sizes, int n_in,
                              void* d_out, int out_size, void* d_ws, size_t ws_size,
                              hipStream_t stream) {
    const float* x      = (const float*)d_in[0];
    const float* weight = (const float*)d_in[1];
    const float* bias   = (const float*)d_in[2];
    const float* res_w  = (const float*)d_in[3];
    const float* res_b  = (const float*)d_in[4];
    const float* gamma  = (const float*)d_in[5];
    const float* beta   = (const float*)d_in[6];
    const float* ew     = (const float*)d_in[7];
    const int*   ei     = (const int*)d_in[8];

    const int E = in_sizes[7];
    const int n_nodes = in_sizes[0] / D_IN;
    float* out = (float*)d_out;

    char* ws = (char*)d_ws;
    ushort_t* wt      = (ushort_t*)ws;                 // 256*256*2 = 131072 B
    ushort_t* support = (ushort_t*)(ws + 131072);      // n*128*2 = 25.6 MB

    k_transpose<<<256, 256, 0, stream>>>(weight, res_w, wt);
    k_gemm<<<(n_nodes + 63) / 64, 256, 0, stream>>>(x, wt, bias, res_b, support, out, n_nodes);
    k_scatter<<<4096, 256, 0, stream>>>(support, ew, ei, out, E);
    k_ln<<<2048, 256, 0, stream>>>(out, gamma, beta, n_nodes);
}

// Round 3
// 1016.161 us; speedup vs baseline: 2.7808x; 2.7808x over previous
//
#include <hip/hip_runtime.h>
#include <hip/hip_bf16.h>

#define D_IN 256
#define D_OUT 128
#define LN_EPS 1e-5f

typedef short bf16x8 __attribute__((ext_vector_type(8)));
typedef float f32x4 __attribute__((ext_vector_type(4)));
typedef unsigned short ushort_t;

__device__ __forceinline__ float b2f(ushort_t u) {
    union { unsigned int i; float f; } v; v.i = (unsigned int)u << 16; return v.f;
}
__device__ __forceinline__ ushort_t f2b(float f) {
    __hip_bfloat16 h = __float2bfloat16(f);
    return *reinterpret_cast<ushort_t*>(&h);
}

// ---------------- Kernel 0: pack+transpose f32 weights into bf16 Wt[n][k], n = [W | res_w] cols
__global__ void k_transpose(const float* __restrict__ w, const float* __restrict__ rw,
                            ushort_t* __restrict__ wt) {
    int idx = blockIdx.x * 256 + threadIdx.x;   // 65536 total
    int n = idx >> 8, k = idx & 255;
    float v = (n < 128) ? w[k * 128 + n] : rw[k * 128 + (n - 128)];
    wt[idx] = f2b(v);
}

__global__ void k_zero(int* __restrict__ p, int n) {
    int i = blockIdx.x * blockDim.x + threadIdx.x;
    if (i < n) p[i] = 0;
}

// ---------------- Kernel 1: dual GEMM (bf16 MFMA internally, f32 in/out)
// support(bf16) = x@W ; out(f32) = bias + relu(x@res_w + res_b)
__launch_bounds__(256)
__global__ void k_gemm(const float* __restrict__ x, const ushort_t* __restrict__ wt,
                       const float* __restrict__ bias, const float* __restrict__ res_b,
                       ushort_t* __restrict__ support, float* __restrict__ out, int n_nodes) {
    __shared__ ushort_t As[64 * 40];
    __shared__ ushort_t Bs[256 * 40];

    const int tid = threadIdx.x;
    const int m0 = blockIdx.x * 64;
    const int wv = tid >> 6, lane = tid & 63;
    const int lm = lane & 15, quad = lane >> 4;
    const int mh = wv >> 1;
    const int nh = wv & 1;

    f32x4 acc[2][8];
#pragma unroll
    for (int i = 0; i < 2; i++)
#pragma unroll
        for (int j = 0; j < 8; j++) acc[i][j] = 0.0f;

    const int arow = tid >> 2, aseg = tid & 3;
    const bool arow_ok = (m0 + arow) < n_nodes;
    const float* xrow = x + (long)(m0 + arow) * D_IN + aseg * 8;

    for (int kc = 0; kc < 8; kc++) {
        __syncthreads();
        {
            bf16x8 av = {0, 0, 0, 0, 0, 0, 0, 0};
            if (arow_ok) {
                f32x4 p0 = *(const f32x4*)(xrow + kc * 32);
                f32x4 p1 = *(const f32x4*)(xrow + kc * 32 + 4);
#pragma unroll
                for (int j = 0; j < 4; j++) { av[j] = (short)f2b(p0[j]); av[4 + j] = (short)f2b(p1[j]); }
            }
            *(bf16x8*)(&As[arow * 40 + aseg * 8]) = av;
        }
#pragma unroll
        for (int i = 0; i < 4; i++) {
            int n = (tid >> 2) + i * 64;
            bf16x8 v = *(const bf16x8*)(wt + n * 256 + kc * 32 + aseg * 8);
            *(bf16x8*)(&Bs[n * 40 + aseg * 8]) = v;
        }
        __syncthreads();

        bf16x8 afr0 = *(const bf16x8*)(&As[(mh * 32 + lm) * 40 + quad * 8]);
        bf16x8 afr1 = *(const bf16x8*)(&As[(mh * 32 + 16 + lm) * 40 + quad * 8]);
#pragma unroll
        for (int nt = 0; nt < 8; nt++) {
            bf16x8 bfr = *(const bf16x8*)(&Bs[(nh * 128 + nt * 16 + lm) * 40 + quad * 8]);
            acc[0][nt] = __builtin_amdgcn_mfma_f32_16x16x32_bf16(afr0, bfr, acc[0][nt], 0, 0, 0);
            acc[1][nt] = __builtin_amdgcn_mfma_f32_16x16x32_bf16(afr1, bfr, acc[1][nt], 0, 0, 0);
        }
    }

#pragma unroll
    for (int i = 0; i < 2; i++) {
#pragma unroll
        for (int nt = 0; nt < 8; nt++) {
            int col = nh * 128 + nt * 16 + lm;
#pragma unroll
            for (int r = 0; r < 4; r++) {
                int node = m0 + mh * 32 + i * 16 + quad * 4 + r;
                if (node >= n_nodes) continue;
                float v = acc[i][nt][r];
                if (col < 128) {
                    support[(long)node * 128 + col] = f2b(v);
                } else {
                    int c2 = col - 128;
                    float t = v + res_b[c2];
                    t = t > 0.0f ? t : 0.0f;
                    out[(long)node * 128 + c2] = t + bias[c2];
                }
            }
        }
    }
}

// ---------------- Kernel 2: histogram of dst
__launch_bounds__(256)
__global__ void k_hist(const int* __restrict__ ei, int* __restrict__ deg, int E) {
    int stride = gridDim.x * blockDim.x;
    for (int e = blockIdx.x * blockDim.x + threadIdx.x; e < E; e += stride)
        atomicAdd(&deg[ei[E + e]], 1);
}

// ---------------- Kernel 3: exclusive scan (single block, 1024 threads)
__launch_bounds__(1024)
__global__ void k_scan(const int* __restrict__ deg, int* __restrict__ offs,
                       int* __restrict__ cursor, int n) {
    __shared__ int part[1024];
    int t = threadIdx.x;
    int chunk = (n + 1023) / 1024;
    int lo = t * chunk, hi = min(lo + chunk, n);
    int s = 0;
    for (int i = lo; i < hi; i++) s += deg[i];
    part[t] = s;
    __syncthreads();
    // Hillis-Steele inclusive scan over 1024 partials
    for (int off = 1; off < 1024; off <<= 1) {
        int v = part[t];
        int add = (t >= off) ? part[t - off] : 0;
        __syncthreads();
        part[t] = v + add;
        __syncthreads();
    }
    int run = part[t] - s;   // exclusive prefix of this thread's chunk
    for (int i = lo; i < hi; i++) {
        offs[i] = run;
        cursor[i] = run;
        run += deg[i];
    }
    if (t == 1023) offs[n] = run;
}

// ---------------- Kernel 4: reorder edges into dst-CSR (src, weight) pairs
__launch_bounds__(256)
__global__ void k_reorder(const int* __restrict__ ei, const float* __restrict__ ew,
                          int* __restrict__ cursor, int2* __restrict__ sorted, int E) {
    int stride = gridDim.x * blockDim.x;
    for (int e = blockIdx.x * blockDim.x + threadIdx.x; e < E; e += stride) {
        int dst = ei[E + e];
        int pos = atomicAdd(&cursor[dst], 1);
        int2 rec;
        rec.x = ei[e];
        rec.y = __float_as_int(ew[e]);
        sorted[pos] = rec;
    }
}

// ---------------- Kernel 5: gather-aggregate + residual + LayerNorm (wave per node)
__launch_bounds__(256)
__global__ void k_agg_ln(const ushort_t* __restrict__ support, const int* __restrict__ offs,
                         const int2* __restrict__ sorted, const float* __restrict__ gamma,
                         const float* __restrict__ beta, float* __restrict__ out, int n_nodes) {
    int gw = (int)((blockIdx.x * blockDim.x + threadIdx.x) >> 6);
    int lane = threadIdx.x & 63;
    int nw = (int)((gridDim.x * blockDim.x) >> 6);
    float g0 = gamma[lane * 2], g1 = gamma[lane * 2 + 1];
    float b0 = beta[lane * 2], b1 = beta[lane * 2 + 1];

    for (int node = gw; node < n_nodes; node += nw) {
        int start = offs[node], end = offs[node + 1];
        float ax = 0.0f, ay = 0.0f;
        for (int base = start; base < end; base += 64) {
            int n = end - base; if (n > 64) n = 64;
            int2 ed = {0, 0};
            if (lane < n) ed = sorted[base + lane];
            for (int j = 0; j < n; j++) {
                int srcj = __builtin_amdgcn_readlane(ed.x, j);
                float wj = __int_as_float(__builtin_amdgcn_readlane(ed.y, j));
                unsigned int v = *(const unsigned int*)(support + (long)srcj * 128 + lane * 2);
                ax += wj * b2f((ushort_t)(v & 0xffffu));
                ay += wj * b2f((ushort_t)(v >> 16));
            }
        }
        // residual branch (bias + relu(x@res_w+res_b)) already in out
        float2 r = *(const float2*)(out + (long)node * 128 + lane * 2);
        float tx = ax + r.x, ty = ay + r.y;
        float s = tx + ty;
        float ss = tx * tx + ty * ty;
#pragma unroll
        for (int off = 1; off < 64; off <<= 1) {
            s += __shfl_xor(s, off, 64);
            ss += __shfl_xor(ss, off, 64);
        }
        float mean = s * (1.0f / 128.0f);
        float var = ss * (1.0f / 128.0f) - mean * mean;
        float rstd = rsqrtf(var + LN_EPS);
        float2 o;
        o.x = (tx - mean) * rstd * g0 + b0;
        o.y = (ty - mean) * rstd * g1 + b1;
        *(float2*)(out + (long)node * 128 + lane * 2) = o;
    }
}

extern "C" void kernel_launch(void* const* d_in, const int* in_sizes, int n_in,
                              void* d_out, int out_size, void* d_ws, size_t ws_size,
                              hipStream_t stream) {
    const float* x      = (const float*)d_in[0];
    const float* weight = (const float*)d_in[1];
    const float* bias   = (const float*)d_in[2];
    const float* res_w  = (const float*)d_in[3];
    const float* res_b  = (const float*)d_in[4];
    const float* gamma  = (const float*)d_in[5];
    const float* beta   = (const float*)d_in[6];
    const float* ew     = (const float*)d_in[7];
    const int*   ei     = (const int*)d_in[8];

    const int E = in_sizes[7];
    const int n_nodes = in_sizes[0] / D_IN;
    float* out = (float*)d_out;

    // workspace layout (256B-aligned regions), total ~52.5 MB
    char* ws = (char*)d_ws;
    size_t off = 0;
    ushort_t* wt = (ushort_t*)(ws + off);        off += 256 * 256 * 2;                    // 128 KB
    ushort_t* support = (ushort_t*)(ws + off);   off += (size_t)n_nodes * 128 * 2;        // 25.6 MB
    off = (off + 255) & ~(size_t)255;
    int* deg = (int*)(ws + off);                 off += (size_t)(n_nodes + 1) * 4;
    off = (off + 255) & ~(size_t)255;
    int* offs = (int*)(ws + off);                off += (size_t)(n_nodes + 1) * 4;
    off = (off + 255) & ~(size_t)255;
    int* cursor = (int*)(ws + off);              off += (size_t)n_nodes * 4;
    off = (off + 255) & ~(size_t)255;
    int2* sorted = (int2*)(ws + off);            off += (size_t)E * 8;                    // 25.6 MB

    k_transpose<<<256, 256, 0, stream>>>(weight, res_w, wt);
    k_zero<<<(n_nodes + 256) / 256, 256, 0, stream>>>(deg, n_nodes + 1);
    k_gemm<<<(n_nodes + 63) / 64, 256, 0, stream>>>(x, wt, bias, res_b, support, out, n_nodes);
    k_hist<<<2048, 256, 0, stream>>>(ei, deg, E);
    k_scan<<<1, 1024, 0, stream>>>(deg, offs, cursor, n_nodes);
    k_reorder<<<2048, 256, 0, stream>>>(ei, ew, cursor, sorted, E);
    k_agg_ln<<<4096, 256, 0, stream>>>(support, offs, sorted, gamma, beta, out, n_nodes);
}

// Round 4
// 537.965 us; speedup vs baseline: 5.2526x; 1.8889x over previous
//
#include <hip/hip_runtime.h>
#include <hip/hip_bf16.h>

#define D_IN 256
#define D_OUT 128
#define LN_EPS 1e-5f
#define NBUCK 256          // coarse buckets, bucket = dst >> 9 (512 nodes each)
#define NCHUNK 256         // edge chunks (one block each) in count/part

typedef short bf16x8 __attribute__((ext_vector_type(8)));
typedef float f32x4 __attribute__((ext_vector_type(4)));
typedef unsigned short ushort_t;

__device__ __forceinline__ float b2f(ushort_t u) {
    union { unsigned int i; float f; } v; v.i = (unsigned int)u << 16; return v.f;
}
__device__ __forceinline__ ushort_t f2b(float f) {
    __hip_bfloat16 h = __float2bfloat16(f);
    return *reinterpret_cast<ushort_t*>(&h);
}

// ---------------- Kernel 0: pack+transpose f32 weights into bf16 Wt[n][k], n = [W | res_w] cols
__global__ void k_transpose(const float* __restrict__ w, const float* __restrict__ rw,
                            ushort_t* __restrict__ wt) {
    int idx = blockIdx.x * 256 + threadIdx.x;   // 65536 total
    int n = idx >> 8, k = idx & 255;
    float v = (n < 128) ? w[k * 128 + n] : rw[k * 128 + (n - 128)];
    wt[idx] = f2b(v);
}

// ---------------- Kernel 1: dual GEMM (bf16 MFMA internally, f32 in/out)
__launch_bounds__(256)
__global__ void k_gemm(const float* __restrict__ x, const ushort_t* __restrict__ wt,
                       const float* __restrict__ bias, const float* __restrict__ res_b,
                       ushort_t* __restrict__ support, float* __restrict__ out, int n_nodes) {
    __shared__ ushort_t As[64 * 40];
    __shared__ ushort_t Bs[256 * 40];

    const int tid = threadIdx.x;
    const int m0 = blockIdx.x * 64;
    const int wv = tid >> 6, lane = tid & 63;
    const int lm = lane & 15, quad = lane >> 4;
    const int mh = wv >> 1;
    const int nh = wv & 1;

    f32x4 acc[2][8];
#pragma unroll
    for (int i = 0; i < 2; i++)
#pragma unroll
        for (int j = 0; j < 8; j++) acc[i][j] = 0.0f;

    const int arow = tid >> 2, aseg = tid & 3;
    const bool arow_ok = (m0 + arow) < n_nodes;
    const float* xrow = x + (long)(m0 + arow) * D_IN + aseg * 8;

    for (int kc = 0; kc < 8; kc++) {
        __syncthreads();
        {
            bf16x8 av = {0, 0, 0, 0, 0, 0, 0, 0};
            if (arow_ok) {
                f32x4 p0 = *(const f32x4*)(xrow + kc * 32);
                f32x4 p1 = *(const f32x4*)(xrow + kc * 32 + 4);
#pragma unroll
                for (int j = 0; j < 4; j++) { av[j] = (short)f2b(p0[j]); av[4 + j] = (short)f2b(p1[j]); }
            }
            *(bf16x8*)(&As[arow * 40 + aseg * 8]) = av;
        }
#pragma unroll
        for (int i = 0; i < 4; i++) {
            int n = (tid >> 2) + i * 64;
            bf16x8 v = *(const bf16x8*)(wt + n * 256 + kc * 32 + aseg * 8);
            *(bf16x8*)(&Bs[n * 40 + aseg * 8]) = v;
        }
        __syncthreads();

        bf16x8 afr0 = *(const bf16x8*)(&As[(mh * 32 + lm) * 40 + quad * 8]);
        bf16x8 afr1 = *(const bf16x8*)(&As[(mh * 32 + 16 + lm) * 40 + quad * 8]);
#pragma unroll
        for (int nt = 0; nt < 8; nt++) {
            bf16x8 bfr = *(const bf16x8*)(&Bs[(nh * 128 + nt * 16 + lm) * 40 + quad * 8]);
            acc[0][nt] = __builtin_amdgcn_mfma_f32_16x16x32_bf16(afr0, bfr, acc[0][nt], 0, 0, 0);
            acc[1][nt] = __builtin_amdgcn_mfma_f32_16x16x32_bf16(afr1, bfr, acc[1][nt], 0, 0, 0);
        }
    }

#pragma unroll
    for (int i = 0; i < 2; i++) {
#pragma unroll
        for (int nt = 0; nt < 8; nt++) {
            int col = nh * 128 + nt * 16 + lm;
#pragma unroll
            for (int r = 0; r < 4; r++) {
                int node = m0 + mh * 32 + i * 16 + quad * 4 + r;
                if (node >= n_nodes) continue;
                float v = acc[i][nt][r];
                if (col < 128) {
                    support[(long)node * 128 + col] = f2b(v);
                } else {
                    int c2 = col - 128;
                    float t = v + res_b[c2];
                    t = t > 0.0f ? t : 0.0f;
                    out[(long)node * 128 + c2] = t + bias[c2];
                }
            }
        }
    }
}

// ---------------- Kernel 2: per-chunk bucket histogram -> cntmat[bucket][chunk]
__launch_bounds__(256)
__global__ void k_count(const int* __restrict__ ei, int* __restrict__ cntmat, int E, int chunk) {
    __shared__ int h[NBUCK];
    int c = blockIdx.x, t = threadIdx.x;
    h[t] = 0;
    __syncthreads();
    int lo = c * chunk, hi = min(lo + chunk, E);
    for (int e = lo + t; e < hi; e += 256)
        atomicAdd(&h[(unsigned)ei[E + e] >> 9], 1);
    __syncthreads();
    cntmat[t * NCHUNK + c] = h[t];
}

// ---------------- Kernel 3a: scan each bucket row of cntmat (exclusive), rowsum out
__launch_bounds__(256)
__global__ void k_scan1(int* __restrict__ cntmat, int* __restrict__ rowsum) {
    __shared__ int sh[256];
    int b = blockIdx.x, t = threadIdx.x;
    int v = cntmat[b * NCHUNK + t];
    sh[t] = v;
    __syncthreads();
    for (int off = 1; off < 256; off <<= 1) {
        int x = sh[t]; int add = (t >= off) ? sh[t - off] : 0;
        __syncthreads(); sh[t] = x + add; __syncthreads();
    }
    cntmat[b * NCHUNK + t] = sh[t] - v;   // exclusive within row
    if (t == 255) rowsum[b] = sh[255];
}

// ---------------- Kernel 3b: scan bucket sums -> bucket_base; also offs[N]=E
__launch_bounds__(256)
__global__ void k_scan2(const int* __restrict__ rowsum, int* __restrict__ bucket_base,
                        int* __restrict__ offs, int n_nodes, int E) {
    __shared__ int sh[256];
    int t = threadIdx.x;
    int v = rowsum[t];
    sh[t] = v;
    __syncthreads();
    for (int off = 1; off < 256; off <<= 1) {
        int x = sh[t]; int add = (t >= off) ? sh[t - off] : 0;
        __syncthreads(); sh[t] = x + add; __syncthreads();
    }
    bucket_base[t] = sh[t] - v;
    if (t == 255) bucket_base[256] = sh[255];
    if (t == 0) offs[n_nodes] = E;
}

// ---------------- Kernel 4: partition edges into buckets, block-private sub-regions
__launch_bounds__(256)
__global__ void k_part(const int* __restrict__ ei, const float* __restrict__ ew,
                       const int* __restrict__ cntmat, const int* __restrict__ bucket_base,
                       int2* __restrict__ srcw, int E, int chunk) {
    __shared__ int cur[NBUCK];
    int c = blockIdx.x, t = threadIdx.x;
    cur[t] = bucket_base[t] + cntmat[t * NCHUNK + c];
    __syncthreads();
    int lo = c * chunk, hi = min(lo + chunk, E);
    for (int e = lo + t; e < hi; e += 256) {
        int src = ei[e];
        int dst = ei[E + e];
        float w = ew[e];
        int b = (unsigned)dst >> 9;
        int pos = atomicAdd(&cur[b], 1);
        int2 rec;
        rec.x = src | ((dst & 511) << 17);   // n_nodes <= 131072
        rec.y = __float_as_int(w);
        srcw[pos] = rec;
    }
}

// ---------------- Kernel 5: per-bucket node CSR: offs[] + perm[] (one block per bucket)
__launch_bounds__(256)
__global__ void k_build(const int2* __restrict__ srcw, const int* __restrict__ bucket_base,
                        int* __restrict__ perm, int* __restrict__ offs, int n_nodes) {
    __shared__ int h[512];
    __shared__ int psum[256];
    int b = blockIdx.x, t = threadIdx.x;
    int start = bucket_base[b], end = bucket_base[b + 1];
    h[t] = 0; h[t + 256] = 0;
    __syncthreads();
    for (int i = start + t; i < end; i += 256)
        atomicAdd(&h[(unsigned)srcw[i].x >> 17], 1);
    __syncthreads();
    int h0 = h[2 * t], h1 = h[2 * t + 1];
    int p = h0 + h1;
    psum[t] = p;
    __syncthreads();
    for (int off = 1; off < 256; off <<= 1) {
        int x = psum[t]; int add = (t >= off) ? psum[t - off] : 0;
        __syncthreads(); psum[t] = x + add; __syncthreads();
    }
    int e0 = psum[t] - p;        // exclusive within bucket
    int e1 = e0 + h0;
    h[2 * t] = e0; h[2 * t + 1] = e1;
    int node0 = b * 512 + 2 * t;
    if (node0 < n_nodes) offs[node0] = start + e0;
    if (node0 + 1 < n_nodes) offs[node0 + 1] = start + e1;
    __syncthreads();
    for (int i = start + t; i < end; i += 256) {
        int dl = (unsigned)srcw[i].x >> 17;
        int pos = start + atomicAdd(&h[dl], 1);
        perm[pos] = i;
    }
}

// ---------------- Kernel 6: gather-aggregate + residual + LayerNorm (wave per node)
__launch_bounds__(256)
__global__ void k_agg_ln(const ushort_t* __restrict__ support, const int* __restrict__ offs,
                         const int* __restrict__ perm, const int2* __restrict__ srcw,
                         const float* __restrict__ gamma, const float* __restrict__ beta,
                         float* __restrict__ out, int n_nodes) {
    int gw = (int)((blockIdx.x * blockDim.x + threadIdx.x) >> 6);
    int lane = threadIdx.x & 63;
    int nw = (int)((gridDim.x * blockDim.x) >> 6);
    float g0 = gamma[lane * 2], g1 = gamma[lane * 2 + 1];
    float b0 = beta[lane * 2], b1 = beta[lane * 2 + 1];

    for (int node = gw; node < n_nodes; node += nw) {
        int start = offs[node], end = offs[node + 1];
        float ax = 0.0f, ay = 0.0f;
        for (int base = start; base < end; base += 64) {
            int n = end - base; if (n > 64) n = 64;
            int2 ed = {0, 0};
            if (lane < n) ed = srcw[perm[base + lane]];
            for (int j = 0; j < n; j++) {
                int srcj = __builtin_amdgcn_readlane(ed.x, j) & 131071;
                float wj = __int_as_float(__builtin_amdgcn_readlane(ed.y, j));
                unsigned int v = *(const unsigned int*)(support + (long)srcj * 128 + lane * 2);
                ax += wj * b2f((ushort_t)(v & 0xffffu));
                ay += wj * b2f((ushort_t)(v >> 16));
            }
        }
        float2 r = *(const float2*)(out + (long)node * 128 + lane * 2);
        float tx = ax + r.x, ty = ay + r.y;
        float s = tx + ty;
        float ss = tx * tx + ty * ty;
#pragma unroll
        for (int off = 1; off < 64; off <<= 1) {
            s += __shfl_xor(s, off, 64);
            ss += __shfl_xor(ss, off, 64);
        }
        float mean = s * (1.0f / 128.0f);
        float var = ss * (1.0f / 128.0f) - mean * mean;
        float rstd = rsqrtf(var + LN_EPS);
        float2 o;
        o.x = (tx - mean) * rstd * g0 + b0;
        o.y = (ty - mean) * rstd * g1 + b1;
        *(float2*)(out + (long)node * 128 + lane * 2) = o;
    }
}

extern "C" void kernel_launch(void* const* d_in, const int* in_sizes, int n_in,
                              void* d_out, int out_size, void* d_ws, size_t ws_size,
                              hipStream_t stream) {
    const float* x      = (const float*)d_in[0];
    const float* weight = (const float*)d_in[1];
    const float* bias   = (const float*)d_in[2];
    const float* res_w  = (const float*)d_in[3];
    const float* res_b  = (const float*)d_in[4];
    const float* gamma  = (const float*)d_in[5];
    const float* beta   = (const float*)d_in[6];
    const float* ew     = (const float*)d_in[7];
    const int*   ei     = (const int*)d_in[8];

    const int E = in_sizes[7];
    const int n_nodes = in_sizes[0] / D_IN;
    const int chunk = (E + NCHUNK - 1) / NCHUNK;
    float* out = (float*)d_out;

    // workspace layout (256B-aligned), total ~64.6 MB
    char* ws = (char*)d_ws;
    size_t off = 0;
    auto alloc = [&](size_t bytes) { void* p = ws + off; off = (off + bytes + 255) & ~(size_t)255; return p; };
    ushort_t* wt      = (ushort_t*)alloc(256 * 256 * 2);                 // 128 KB
    ushort_t* support = (ushort_t*)alloc((size_t)n_nodes * 128 * 2);     // 25.6 MB
    int* cntmat       = (int*)alloc((size_t)NBUCK * NCHUNK * 4);         // 256 KB
    int* rowsum       = (int*)alloc(NBUCK * 4);
    int* bucket_base  = (int*)alloc((NBUCK + 1) * 4);
    int* offs         = (int*)alloc((size_t)(n_nodes + 1) * 4);          // 400 KB
    int2* srcw        = (int2*)alloc((size_t)E * 8);                     // 25.6 MB
    int* perm         = (int*)alloc((size_t)E * 4);                      // 12.8 MB

    k_transpose<<<256, 256, 0, stream>>>(weight, res_w, wt);
    k_gemm<<<(n_nodes + 63) / 64, 256, 0, stream>>>(x, wt, bias, res_b, support, out, n_nodes);
    k_count<<<NCHUNK, 256, 0, stream>>>(ei, cntmat, E, chunk);
    k_scan1<<<NBUCK, 256, 0, stream>>>(cntmat, rowsum);
    k_scan2<<<1, 256, 0, stream>>>(rowsum, bucket_base, offs, n_nodes, E);
    k_part<<<NCHUNK, 256, 0, stream>>>(ei, ew, cntmat, bucket_base, srcw, E, chunk);
    k_build<<<NBUCK, 256, 0, stream>>>(srcw, bucket_base, perm, offs, n_nodes);
    k_agg_ln<<<4096, 256, 0, stream>>>(support, offs, perm, srcw, gamma, beta, out, n_nodes);
}

// Round 5
// 505.095 us; speedup vs baseline: 5.5944x; 1.0651x over previous
//
#include <hip/hip_runtime.h>
#include <hip/hip_bf16.h>

#define D_IN 256
#define D_OUT 128
#define LN_EPS 1e-5f
#define NBUCK 256          // coarse buckets, bucket = dst >> 9 (512 nodes each)
#define NCHUNK 256         // edge chunks (one block each) in count/part

typedef short bf16x8 __attribute__((ext_vector_type(8)));
typedef float f32x4 __attribute__((ext_vector_type(4)));
typedef unsigned short ushort_t;

__device__ __forceinline__ float b2f(ushort_t u) {
    union { unsigned int i; float f; } v; v.i = (unsigned int)u << 16; return v.f;
}
__device__ __forceinline__ ushort_t f2b(float f) {
    __hip_bfloat16 h = __float2bfloat16(f);
    return *reinterpret_cast<ushort_t*>(&h);
}

// ---------------- Kernel 0: pack+transpose f32 weights into bf16 Wt[n][k], n = [W | res_w] cols
__global__ void k_transpose(const float* __restrict__ w, const float* __restrict__ rw,
                            ushort_t* __restrict__ wt) {
    int idx = blockIdx.x * 256 + threadIdx.x;   // 65536 total
    int n = idx >> 8, k = idx & 255;
    float v = (n < 128) ? w[k * 128 + n] : rw[k * 128 + (n - 128)];
    wt[idx] = f2b(v);
}

// ---------------- Kernel 1: dual GEMM (bf16 MFMA internally, f32 in/out)
__launch_bounds__(256)
__global__ void k_gemm(const float* __restrict__ x, const ushort_t* __restrict__ wt,
                       const float* __restrict__ bias, const float* __restrict__ res_b,
                       ushort_t* __restrict__ support, float* __restrict__ out, int n_nodes) {
    __shared__ ushort_t As[64 * 40];
    __shared__ ushort_t Bs[256 * 40];

    const int tid = threadIdx.x;
    const int m0 = blockIdx.x * 64;
    const int wv = tid >> 6, lane = tid & 63;
    const int lm = lane & 15, quad = lane >> 4;
    const int mh = wv >> 1;
    const int nh = wv & 1;

    f32x4 acc[2][8];
#pragma unroll
    for (int i = 0; i < 2; i++)
#pragma unroll
        for (int j = 0; j < 8; j++) acc[i][j] = 0.0f;

    const int arow = tid >> 2, aseg = tid & 3;
    const bool arow_ok = (m0 + arow) < n_nodes;
    const float* xrow = x + (long)(m0 + arow) * D_IN + aseg * 8;

    for (int kc = 0; kc < 8; kc++) {
        __syncthreads();
        {
            bf16x8 av = {0, 0, 0, 0, 0, 0, 0, 0};
            if (arow_ok) {
                f32x4 p0 = *(const f32x4*)(xrow + kc * 32);
                f32x4 p1 = *(const f32x4*)(xrow + kc * 32 + 4);
#pragma unroll
                for (int j = 0; j < 4; j++) { av[j] = (short)f2b(p0[j]); av[4 + j] = (short)f2b(p1[j]); }
            }
            *(bf16x8*)(&As[arow * 40 + aseg * 8]) = av;
        }
#pragma unroll
        for (int i = 0; i < 4; i++) {
            int n = (tid >> 2) + i * 64;
            bf16x8 v = *(const bf16x8*)(wt + n * 256 + kc * 32 + aseg * 8);
            *(bf16x8*)(&Bs[n * 40 + aseg * 8]) = v;
        }
        __syncthreads();

        bf16x8 afr0 = *(const bf16x8*)(&As[(mh * 32 + lm) * 40 + quad * 8]);
        bf16x8 afr1 = *(const bf16x8*)(&As[(mh * 32 + 16 + lm) * 40 + quad * 8]);
#pragma unroll
        for (int nt = 0; nt < 8; nt++) {
            bf16x8 bfr = *(const bf16x8*)(&Bs[(nh * 128 + nt * 16 + lm) * 40 + quad * 8]);
            acc[0][nt] = __builtin_amdgcn_mfma_f32_16x16x32_bf16(afr0, bfr, acc[0][nt], 0, 0, 0);
            acc[1][nt] = __builtin_amdgcn_mfma_f32_16x16x32_bf16(afr1, bfr, acc[1][nt], 0, 0, 0);
        }
    }

#pragma unroll
    for (int i = 0; i < 2; i++) {
#pragma unroll
        for (int nt = 0; nt < 8; nt++) {
            int col = nh * 128 + nt * 16 + lm;
#pragma unroll
            for (int r = 0; r < 4; r++) {
                int node = m0 + mh * 32 + i * 16 + quad * 4 + r;
                if (node >= n_nodes) continue;
                float v = acc[i][nt][r];
                if (col < 128) {
                    support[(long)node * 128 + col] = f2b(v);
                } else {
                    int c2 = col - 128;
                    float t = v + res_b[c2];
                    t = t > 0.0f ? t : 0.0f;
                    out[(long)node * 128 + c2] = t + bias[c2];
                }
            }
        }
    }
}

// ---------------- Kernel 2: per-chunk bucket histogram -> cntmat[bucket][chunk]
__launch_bounds__(256)
__global__ void k_count(const int* __restrict__ ei, int* __restrict__ cntmat, int E, int chunk) {
    __shared__ int h[NBUCK];
    int c = blockIdx.x, t = threadIdx.x;
    h[t] = 0;
    __syncthreads();
    int lo = c * chunk, hi = min(lo + chunk, E);
    for (int e = lo + t; e < hi; e += 256)
        atomicAdd(&h[(unsigned)ei[E + e] >> 9], 1);
    __syncthreads();
    cntmat[t * NCHUNK + c] = h[t];
}

// ---------------- Kernel 3a: scan each bucket row of cntmat (exclusive), rowsum out
__launch_bounds__(256)
__global__ void k_scan1(int* __restrict__ cntmat, int* __restrict__ rowsum) {
    __shared__ int sh[256];
    int b = blockIdx.x, t = threadIdx.x;
    int v = cntmat[b * NCHUNK + t];
    sh[t] = v;
    __syncthreads();
    for (int off = 1; off < 256; off <<= 1) {
        int x = sh[t]; int add = (t >= off) ? sh[t - off] : 0;
        __syncthreads(); sh[t] = x + add; __syncthreads();
    }
    cntmat[b * NCHUNK + t] = sh[t] - v;
    if (t == 255) rowsum[b] = sh[255];
}

// ---------------- Kernel 3b: scan bucket sums -> bucket_base; also offs[N]=E
__launch_bounds__(256)
__global__ void k_scan2(const int* __restrict__ rowsum, int* __restrict__ bucket_base,
                        int* __restrict__ offs, int n_nodes, int E) {
    __shared__ int sh[256];
    int t = threadIdx.x;
    int v = rowsum[t];
    sh[t] = v;
    __syncthreads();
    for (int off = 1; off < 256; off <<= 1) {
        int x = sh[t]; int add = (t >= off) ? sh[t - off] : 0;
        __syncthreads(); sh[t] = x + add; __syncthreads();
    }
    bucket_base[t] = sh[t] - v;
    if (t == 255) bucket_base[256] = sh[255];
    if (t == 0) offs[n_nodes] = E;
}

// ---------------- Kernel 4: partition edges into buckets (block-private sub-regions)
// pk = dl<<17 | src  (4B), pw = weight bf16 (2B)
__launch_bounds__(256)
__global__ void k_part(const int* __restrict__ ei, const float* __restrict__ ew,
                       const int* __restrict__ cntmat, const int* __restrict__ bucket_base,
                       int* __restrict__ pk, ushort_t* __restrict__ pw, int E, int chunk) {
    __shared__ int cur[NBUCK];
    int c = blockIdx.x, t = threadIdx.x;
    cur[t] = bucket_base[t] + cntmat[t * NCHUNK + c];
    __syncthreads();
    int lo = c * chunk, hi = min(lo + chunk, E);
    for (int e = lo + t; e < hi; e += 256) {
        int src = ei[e];
        int dst = ei[E + e];
        float w = ew[e];
        int b = (unsigned)dst >> 9;
        int pos = atomicAdd(&cur[b], 1);
        pk[pos] = src | ((dst & 511) << 17);
        pw[pos] = f2b(w);
    }
}

// ---------------- Kernel 5: per-bucket node-sort: write sorted records + offs
__launch_bounds__(256)
__global__ void k_build(const int* __restrict__ pk, const ushort_t* __restrict__ pw,
                        const int* __restrict__ bucket_base, int* __restrict__ sk,
                        ushort_t* __restrict__ sw, int* __restrict__ offs, int n_nodes) {
    __shared__ int h[512];
    __shared__ int psum[256];
    int b = blockIdx.x, t = threadIdx.x;
    int start = bucket_base[b], end = bucket_base[b + 1];
    h[t] = 0; h[t + 256] = 0;
    __syncthreads();
    for (int i = start + t; i < end; i += 256)
        atomicAdd(&h[(unsigned)pk[i] >> 17], 1);
    __syncthreads();
    int h0 = h[2 * t], h1 = h[2 * t + 1];
    int p = h0 + h1;
    psum[t] = p;
    __syncthreads();
    for (int off = 1; off < 256; off <<= 1) {
        int x = psum[t]; int add = (t >= off) ? psum[t - off] : 0;
        __syncthreads(); psum[t] = x + add; __syncthreads();
    }
    int e0 = psum[t] - p;
    int e1 = e0 + h0;
    h[2 * t] = e0; h[2 * t + 1] = e1;
    int node0 = b * 512 + 2 * t;
    if (node0 < n_nodes) offs[node0] = start + e0;
    if (node0 + 1 < n_nodes) offs[node0 + 1] = start + e1;
    __syncthreads();
    for (int i = start + t; i < end; i += 256) {
        int key = pk[i];
        int dl = (unsigned)key >> 17;
        int pos = start + atomicAdd(&h[dl], 1);
        sk[pos] = key;
        sw[pos] = pw[i];
    }
}

// ---------------- Kernel 6: gather-aggregate + residual + LayerNorm (wave per node)
__launch_bounds__(256)
__global__ void k_agg_ln(const ushort_t* __restrict__ support, const int* __restrict__ offs,
                         const int* __restrict__ sk, const ushort_t* __restrict__ sw,
                         const float* __restrict__ gamma, const float* __restrict__ beta,
                         float* __restrict__ out, int n_nodes) {
    int gw = (int)((blockIdx.x * blockDim.x + threadIdx.x) >> 6);
    int lane = threadIdx.x & 63;
    int nw = (int)((gridDim.x * blockDim.x) >> 6);
    float g0 = gamma[lane * 2], g1 = gamma[lane * 2 + 1];
    float b0 = beta[lane * 2], b1 = beta[lane * 2 + 1];

    for (int node = gw; node < n_nodes; node += nw) {
        int start = offs[node], end = offs[node + 1];
        float ax = 0.0f, ay = 0.0f;
        for (int base = start; base < end; base += 64) {
            int n = end - base; if (n > 64) n = 64;
            int key = 0, wbits = 0;
            if (lane < n) {
                key = sk[base + lane];
                wbits = (int)sw[base + lane];
            }
            int j = 0;
            for (; j + 4 <= n; j += 4) {
                int s0 = __builtin_amdgcn_readlane(key, j + 0) & 131071;
                int s1 = __builtin_amdgcn_readlane(key, j + 1) & 131071;
                int s2 = __builtin_amdgcn_readlane(key, j + 2) & 131071;
                int s3 = __builtin_amdgcn_readlane(key, j + 3) & 131071;
                float w0 = b2f((ushort_t)__builtin_amdgcn_readlane(wbits, j + 0));
                float w1 = b2f((ushort_t)__builtin_amdgcn_readlane(wbits, j + 1));
                float w2 = b2f((ushort_t)__builtin_amdgcn_readlane(wbits, j + 2));
                float w3 = b2f((ushort_t)__builtin_amdgcn_readlane(wbits, j + 3));
                unsigned int v0 = *(const unsigned int*)(support + (long)s0 * 128 + lane * 2);
                unsigned int v1 = *(const unsigned int*)(support + (long)s1 * 128 + lane * 2);
                unsigned int v2 = *(const unsigned int*)(support + (long)s2 * 128 + lane * 2);
                unsigned int v3 = *(const unsigned int*)(support + (long)s3 * 128 + lane * 2);
                ax += w0 * b2f((ushort_t)(v0 & 0xffffu)) + w1 * b2f((ushort_t)(v1 & 0xffffu))
                    + w2 * b2f((ushort_t)(v2 & 0xffffu)) + w3 * b2f((ushort_t)(v3 & 0xffffu));
                ay += w0 * b2f((ushort_t)(v0 >> 16)) + w1 * b2f((ushort_t)(v1 >> 16))
                    + w2 * b2f((ushort_t)(v2 >> 16)) + w3 * b2f((ushort_t)(v3 >> 16));
            }
            for (; j < n; j++) {
                int sj = __builtin_amdgcn_readlane(key, j) & 131071;
                float wj = b2f((ushort_t)__builtin_amdgcn_readlane(wbits, j));
                unsigned int v = *(const unsigned int*)(support + (long)sj * 128 + lane * 2);
                ax += wj * b2f((ushort_t)(v & 0xffffu));
                ay += wj * b2f((ushort_t)(v >> 16));
            }
        }
        float2 r = *(const float2*)(out + (long)node * 128 + lane * 2);
        float tx = ax + r.x, ty = ay + r.y;
        float s = tx + ty;
        float ss = tx * tx + ty * ty;
#pragma unroll
        for (int off = 1; off < 64; off <<= 1) {
            s += __shfl_xor(s, off, 64);
            ss += __shfl_xor(ss, off, 64);
        }
        float mean = s * (1.0f / 128.0f);
        float var = ss * (1.0f / 128.0f) - mean * mean;
        float rstd = rsqrtf(var + LN_EPS);
        float2 o;
        o.x = (tx - mean) * rstd * g0 + b0;
        o.y = (ty - mean) * rstd * g1 + b1;
        *(float2*)(out + (long)node * 128 + lane * 2) = o;
    }
}

extern "C" void kernel_launch(void* const* d_in, const int* in_sizes, int n_in,
                              void* d_out, int out_size, void* d_ws, size_t ws_size,
                              hipStream_t stream) {
    const float* x      = (const float*)d_in[0];
    const float* weight = (const float*)d_in[1];
    const float* bias   = (const float*)d_in[2];
    const float* res_w  = (const float*)d_in[3];
    const float* res_b  = (const float*)d_in[4];
    const float* gamma  = (const float*)d_in[5];
    const float* beta   = (const float*)d_in[6];
    const float* ew     = (const float*)d_in[7];
    const int*   ei     = (const int*)d_in[8];

    const int E = in_sizes[7];
    const int n_nodes = in_sizes[0] / D_IN;
    const int chunk = (E + NCHUNK - 1) / NCHUNK;
    float* out = (float*)d_out;

    // workspace layout (256B-aligned), total ~65 MB
    char* ws = (char*)d_ws;
    size_t off = 0;
    auto alloc = [&](size_t bytes) { void* p = ws + off; off = (off + bytes + 255) & ~(size_t)255; return p; };
    ushort_t* wt      = (ushort_t*)alloc(256 * 256 * 2);                 // 128 KB
    ushort_t* support = (ushort_t*)alloc((size_t)n_nodes * 128 * 2);     // 25.6 MB
    int* cntmat       = (int*)alloc((size_t)NBUCK * NCHUNK * 4);         // 256 KB
    int* rowsum       = (int*)alloc(NBUCK * 4);
    int* bucket_base  = (int*)alloc((NBUCK + 1) * 4);
    int* offs         = (int*)alloc((size_t)(n_nodes + 1) * 4);          // 400 KB
    int* pk           = (int*)alloc((size_t)E * 4);                      // 12.8 MB
    ushort_t* pw      = (ushort_t*)alloc((size_t)E * 2);                 // 6.4 MB
    int* sk           = (int*)alloc((size_t)E * 4);                      // 12.8 MB
    ushort_t* sw      = (ushort_t*)alloc((size_t)E * 2);                 // 6.4 MB

    k_transpose<<<256, 256, 0, stream>>>(weight, res_w, wt);
    k_gemm<<<(n_nodes + 63) / 64, 256, 0, stream>>>(x, wt, bias, res_b, support, out, n_nodes);
    k_count<<<NCHUNK, 256, 0, stream>>>(ei, cntmat, E, chunk);
    k_scan1<<<NBUCK, 256, 0, stream>>>(cntmat, rowsum);
    k_scan2<<<1, 256, 0, stream>>>(rowsum, bucket_base, offs, n_nodes, E);
    k_part<<<NCHUNK, 256, 0, stream>>>(ei, ew, cntmat, bucket_base, pk, pw, E, chunk);
    k_build<<<NBUCK, 256, 0, stream>>>(pk, pw, bucket_base, sk, sw, offs, n_nodes);
    k_agg_ln<<<4096, 256, 0, stream>>>(support, offs, sk, sw, gamma, beta, out, n_nodes);
}